// Round 3
// baseline (612.273 us; speedup 1.0000x reference)
//
#include <hip/hip_runtime.h>
#include <hip/hip_bf16.h>
#include <cstdint>

// B=2, T=2048, HID=1024, H=16, DK=DV=64, K(conv)=4. fp32 in/out.
// ws: 4 bf16 planes (32 MB) [+ optional 5th plane xb if ws_size >= 40 MB].
// d_out as scratch: betab fp32 transposed [16][4096] at [0,256K); G=beta*kk
// fp32 [16][4096] at [256K,512K); scan output plane ob bf16 at [8M,16M).
// All dead before the final GEMM writes d_out.
//
// Scan: 512 blocks x 64 thr; block owns 4 DV rows; 16 lanes/row.
// LOOK-AHEAD TRANSFORM: dot_t = a_{t-1}*u_t - cc_{t-1}*kk_t, u_t = S_{t-2}.k_t,
// G_t = beta_t*(k_{t-1}.k_t) precomputed -> serial chain = 1 fma/step.
// CHUNK-BULK LDS: all 16 steps' operands are loaded to registers with ~28
// ds_read_b128 at chunk start (ONE lgkmcnt wait per chunk). Requires the full
// VGPR budget: __launch_bounds__(64, 1) (R2's 88-VGPR cap forced the compiler
// to sink the reads back into the loop -> per-step LDS stalls).

using bf16 = __hip_bfloat16;
typedef __bf16 bf16x8 __attribute__((ext_vector_type(8)));
typedef __bf16 bf16x4v __attribute__((ext_vector_type(4)));
typedef float f32x4 __attribute__((ext_vector_type(4)));
typedef float f32x2 __attribute__((ext_vector_type(2)));
typedef unsigned int u32x4 __attribute__((ext_vector_type(4)));
typedef unsigned int u32x2 __attribute__((ext_vector_type(2)));

__device__ __forceinline__ __bf16 cvt_bf16(float f) {
  __hip_bfloat16 h = (__hip_bfloat16)f;
  return *reinterpret_cast<__bf16*>(&h);
}
__device__ __forceinline__ void async_copy16(const void* g, void* l) {
  __builtin_amdgcn_global_load_lds((const __attribute__((address_space(1))) void*)g,
                                   (__attribute__((address_space(3))) void*)l,
                                   16, 0, 0);
}
__device__ __forceinline__ float bcf(unsigned int u) { return __builtin_bit_cast(float, u); }
template <int CTRL>
__device__ __forceinline__ float dpp_f(float x) {
  int y = __builtin_amdgcn_update_dpp(0, __builtin_bit_cast(int, x), CTRL, 0xF, 0xF, true);
  return __builtin_bit_cast(float, y);
}

// fp32 -> bf16 plane (4M elements)
__global__ __launch_bounds__(256) void cvt_plane_kernel(
    const float* __restrict__ in, bf16* __restrict__ out)
{
  size_t i = ((size_t)blockIdx.x * 256 + threadIdx.x) * 4;
  float4 f = *(const float4*)(in + i);
  bf16x4v t;
  t[0] = cvt_bf16(f.x); t[1] = cvt_bf16(f.y); t[2] = cvt_bf16(f.z); t[3] = cvt_bf16(f.w);
  *(bf16x4v*)((__bf16*)out + i) = t;
}

// C = A * Bt^T. A: MxK (bf16 async-staged unless A_FP32); Bt: NxK fp32.
// MODE 2: raw->bf16; 3: sigmoid(acc+bias)->bf16; 4: raw->fp32; 5: sigmoid(acc+bias)->fp32 TRANSPOSED
template <int MODE, bool A_FP32>
__global__ __launch_bounds__(256) void gemm_bt(
    const void* __restrict__ Av, const float* __restrict__ Bt,
    const float* __restrict__ bias, float* __restrict__ Cf, bf16* __restrict__ Cb,
    int M, int N, int K)
{
  __shared__ __align__(16) __bf16 As[128 * 32];
  __shared__ __align__(16) __bf16 Bs[128 * 32];

  const int tid  = threadIdx.x;
  const int lane = tid & 63;
  const int wave = tid >> 6;
  const int tile_m = blockIdx.y * 128;
  const int tile_n = blockIdx.x * 128;
  const int wm = (wave >> 1) * 64;
  const int wn = (wave & 1) * 64;

  const int srow = lane >> 2;
  const int scol = (lane & 3) * 8;

  f32x4 acc[4][4];
#pragma unroll
  for (int i = 0; i < 4; ++i)
#pragma unroll
    for (int j = 0; j < 4; ++j) acc[i][j] = {0.f, 0.f, 0.f, 0.f};

  for (int k0 = 0; k0 < K; k0 += 32) {
    float4 b0[2], b1[2], a0[2], a1[2];
#pragma unroll
    for (int s = 0; s < 2; ++s) {
      int brow = tile_n + s * 64 + wave * 16 + srow;
      if (brow > N - 1) brow = N - 1;             // clamp (beta GEMM: N=16)
      const float* bp = Bt + (size_t)brow * K + k0 + scol;
      b0[s] = *(const float4*)bp;
      b1[s] = *(const float4*)(bp + 4);
      if (A_FP32) {
        int arow = tile_m + s * 64 + wave * 16 + srow;
        const float* ap = (const float*)Av + (size_t)arow * K + k0 + scol;
        a0[s] = *(const float4*)ap;
        a1[s] = *(const float4*)(ap + 4);
      }
    }
    __syncthreads();
#pragma unroll
    for (int s = 0; s < 2; ++s) {
      if (!A_FP32) {
        int arow = tile_m + s * 64 + wave * 16 + srow;
        async_copy16((const __bf16*)Av + (size_t)arow * K + k0 + scol,
                     &As[(s * 64 + wave * 16 + srow) * 32 + scol]);
      } else {
        bf16x8 ua;
        ua[0] = cvt_bf16(a0[s].x); ua[1] = cvt_bf16(a0[s].y);
        ua[2] = cvt_bf16(a0[s].z); ua[3] = cvt_bf16(a0[s].w);
        ua[4] = cvt_bf16(a1[s].x); ua[5] = cvt_bf16(a1[s].y);
        ua[6] = cvt_bf16(a1[s].z); ua[7] = cvt_bf16(a1[s].w);
        *(bf16x8*)&As[(s * 64 + wave * 16 + srow) * 32 + scol] = ua;
      }
      bf16x8 u;
      u[0] = cvt_bf16(b0[s].x); u[1] = cvt_bf16(b0[s].y);
      u[2] = cvt_bf16(b0[s].z); u[3] = cvt_bf16(b0[s].w);
      u[4] = cvt_bf16(b1[s].x); u[5] = cvt_bf16(b1[s].y);
      u[6] = cvt_bf16(b1[s].z); u[7] = cvt_bf16(b1[s].w);
      *(bf16x8*)&Bs[(s * 64 + wave * 16 + srow) * 32 + scol] = u;
    }
    __syncthreads();

    bf16x8 af[4], bfr[4];
#pragma unroll
    for (int i = 0; i < 4; ++i)
      af[i] = *(const bf16x8*)&As[(wm + i * 16 + (lane & 15)) * 32 + (lane >> 4) * 8];
#pragma unroll
    for (int j = 0; j < 4; ++j)
      bfr[j] = *(const bf16x8*)&Bs[(wn + j * 16 + (lane & 15)) * 32 + (lane >> 4) * 8];

#pragma unroll
    for (int i = 0; i < 4; ++i)
#pragma unroll
      for (int j = 0; j < 4; ++j)
        acc[i][j] = __builtin_amdgcn_mfma_f32_16x16x32_bf16(af[i], bfr[j], acc[i][j], 0, 0, 0);
  }

  // C/D layout (m89-verified): col = lane&15, row = (lane>>4)*4 + reg
#pragma unroll
  for (int i = 0; i < 4; ++i) {
#pragma unroll
    for (int j = 0; j < 4; ++j) {
#pragma unroll
      for (int r = 0; r < 4; ++r) {
        int gm = tile_m + wm + i * 16 + (lane >> 4) * 4 + r;
        int gn = tile_n + wn + j * 16 + (lane & 15);
        if (gn < N) {
          float val = acc[i][j][r];
          if (MODE == 3 || MODE == 5) {
            float bv = bias ? bias[gn] : 0.f;
            val = 1.f / (1.f + __expf(-(val + bv)));
          }
          if (MODE == 4)      Cf[(size_t)gm * N + gn] = val;
          else if (MODE == 5) Cf[(size_t)gn * M + gm] = val;   // transposed
          else                Cb[(size_t)gm * N + gn] = (bf16)val;
        }
      }
    }
  }
}

// causal depthwise conv K=4 + bias + SiLU (+scale). z: [B*T,1024] bf16 plane.
__global__ __launch_bounds__(256) void conv_silu_kernel(
    const bf16* __restrict__ z, const float* __restrict__ w,
    const float* __restrict__ bias, bf16* __restrict__ out, float scale)
{
  int idx = blockIdx.x * 256 + threadIdx.x;
  int c = idx & 1023;
  int m = idx >> 10;
  int t = m & 2047;
  float w0 = w[c * 4 + 0], w1 = w[c * 4 + 1], w2 = w[c * 4 + 2], w3 = w[c * 4 + 3];
  float acc = bias[c] + (float)z[idx] * w3;
  if (t >= 1) acc += (float)z[idx - 1024] * w2;
  if (t >= 2) acc += (float)z[idx - 2048] * w1;
  if (t >= 3) acc += (float)z[idx - 3072] * w0;
  float s = acc / (1.f + __expf(-acc));
  out[idx] = (bf16)(s * scale);
}

// G[h][b*2048+t] = beta[h][b*2048+t] * (k_{t-1} . k_t) over DK=64 (0 at t=0).
__global__ __launch_bounds__(256) void kk_kernel(
    const bf16* __restrict__ k, const float* __restrict__ betab,
    float* __restrict__ G)
{
  int tid = blockIdx.x * 256 + threadIdx.x;
  int out = tid >> 2;            // h*4096 + m, m = b*2048+t
  int j   = tid & 3;
  int h = out >> 12;
  int m = out & 4095;
  int t = m & 2047;
  float s = 0.f;
  if (t > 0) {
    const __bf16* r1 = (const __bf16*)k + (size_t)m * 1024 + h * 64 + j * 16;
    const __bf16* r0 = r1 - 1024;
    bf16x8 a0 = *(const bf16x8*)r0;
    bf16x8 a1 = *(const bf16x8*)(r0 + 8);
    bf16x8 b0 = *(const bf16x8*)r1;
    bf16x8 b1 = *(const bf16x8*)(r1 + 8);
#pragma unroll
    for (int e = 0; e < 8; ++e)
      s += (float)a0[e] * (float)b0[e] + (float)a1[e] * (float)b1[e];
  }
  s += __shfl_xor(s, 1);
  s += __shfl_xor(s, 2);
  if (j == 0) G[out] = betab[out] * s;
}

// delta-rule scan with look-ahead + chunk-bulk register operands.
// 512 blocks (b,h,qd) x 64 thr; block owns DV rows [qd*4, qd*4+4).
// Lane (r4=lane>>4, sg=lane&15) holds S[r4][sg*4..+4) fp32.
// __launch_bounds__(64, 1): grid is 0.5 waves/SIMD anyway -> take the full
// VGPR budget so the 28 chunk-bulk ds_reads stay hoisted + register-resident.
__global__ __launch_bounds__(64, 1) void scan_kernel(
    const bf16* __restrict__ q, const bf16* __restrict__ k,
    const bf16* __restrict__ v, const bf16* __restrict__ a,
    const float* __restrict__ betab, const float* __restrict__ gkk,
    bf16* __restrict__ o)
{
  const int blk = blockIdx.x;
  const int qd = blk >> 5;           // DV slice 0..15 (4 rows each)
  const int bh = blk & 31;
  const int b = bh >> 4, h = bh & 15;
  const int lane = threadIdx.x;      // single wave
  const int r4 = lane >> 4;          // local row 0..3
  const int sg = lane & 15;

  // transposed chunk staging: [sg][18 slots of 4 bf16] (144B stride)
  __shared__ __align__(16) __bf16 skT[2][16][72];    // 4608 B
  __shared__ __align__(16) __bf16 sqT[2][16][72];    // 4608 B
  __shared__ __align__(16) __bf16 svaT[2][2][4][16]; // 512 B [buf][v/a][row][step]
  __shared__ __align__(16) float  so[16][68];        // 4352 B (balanced banks)
  __shared__ __align__(16) __bf16 so2[16][4];        // reduced outputs
  __shared__ float sbeta[2048];                      // 8 KB
  __shared__ float sG[2048];                         // 8 KB  beta*kk

  {
    const float* bp = betab + (size_t)h * 4096 + b * 2048;
    const float* gp = gkk   + (size_t)h * 4096 + b * 2048;
    for (int t = lane; t < 2048; t += 64) { sbeta[t] = bp[t]; sG[t] = gp[t]; }
  }

  const size_t bkq = (size_t)b * 2048 * 1024 + h * 64;   // k/q plane base
  const size_t bva = bkq + qd * 4;                       // v/a/o slice base
  const __bf16* kp = (const __bf16*)k;
  const __bf16* qp = (const __bf16*)q;

  const int g_st = lane >> 3;          // staging step-in-group 0..7
  const int g_cg = (lane & 7) * 8;     // staging col (bf16 units)
  const int sgp  = (lane & 7) * 2;     // sg-slice pair base for commit
  const int va_vh = (lane >> 4) & 1;   // lanes 0-15: v, 16-31: a
  const int va_st = lane & 15;

  bf16x8 pk[2], pq[2];
  bf16x4v pva;
  auto fetch = [&](int t0) {
#pragma unroll
    for (int j = 0; j < 2; ++j) {
      int st = t0 + j * 8 + g_st;
      pk[j] = *(const bf16x8*)(kp + bkq + (size_t)st * 1024 + g_cg);
      pq[j] = *(const bf16x8*)(qp + bkq + (size_t)st * 1024 + g_cg);
    }
    if (lane < 32) {
      const __bf16* src = va_vh ? (const __bf16*)a : (const __bf16*)v;
      pva = *(const bf16x4v*)(src + bva + (size_t)(t0 + va_st) * 1024);
    }
  };
  auto commit = [&](int cb) {
#pragma unroll
    for (int j = 0; j < 2; ++j) {
      int stl = j * 8 + g_st;          // step in chunk 0..15
      u32x4 wk = __builtin_bit_cast(u32x4, pk[j]);
      u32x4 wq = __builtin_bit_cast(u32x4, pq[j]);
      u32x2 lo, hi;
      lo[0] = wk[0]; lo[1] = wk[1]; hi[0] = wk[2]; hi[1] = wk[3];
      *(u32x2*)&skT[cb][sgp][stl * 4]     = lo;
      *(u32x2*)&skT[cb][sgp + 1][stl * 4] = hi;
      lo[0] = wq[0]; lo[1] = wq[1]; hi[0] = wq[2]; hi[1] = wq[3];
      *(u32x2*)&sqT[cb][sgp][stl * 4]     = lo;
      *(u32x2*)&sqT[cb][sgp + 1][stl * 4] = hi;
    }
    if (lane < 32) {
#pragma unroll
      for (int r = 0; r < 4; ++r) svaT[cb][va_vh][r][va_st] = pva[r];
    }
  };

  fetch(0); commit(0);

  f32x2 S2[2];
  S2[0] = {0.f, 0.f}; S2[1] = {0.f, 0.f};
  f32x2 Sold0 = {0.f, 0.f}, Sold1 = {0.f, 0.f};
  float u = 0.f, cc = 0.f, aprev = 0.f;
  __syncthreads();

  auto unpk = [&](unsigned int w) -> f32x2 {
    f32x2 r; r[0] = bcf(w << 16); r[1] = bcf(w & 0xffff0000u); return r;
  };

  for (int c = 0; c < 128; ++c) {
    const int buf = c & 1;
    const bool hasNext = (c + 1 < 128);

    if (hasNext) fetch((c + 1) * 16);   // issue VMEM before the lgkm wait below

    // ---- bulk LDS -> reg: one wait per chunk ----
    u32x4 kw[8], qw[8], vw[2], aw[2];
#pragma unroll
    for (int r = 0; r < 8; ++r) {
      kw[r] = *(const u32x4*)&skT[buf][sg][r * 8];
      qw[r] = *(const u32x4*)&sqT[buf][sg][r * 8];
    }
    vw[0] = *(const u32x4*)&svaT[buf][0][r4][0];
    vw[1] = *(const u32x4*)&svaT[buf][0][r4][8];
    aw[0] = *(const u32x4*)&svaT[buf][1][r4][0];
    aw[1] = *(const u32x4*)&svaT[buf][1][r4][8];
    f32x4 bw[4], gw[4];
#pragma unroll
    for (int r = 0; r < 4; ++r) {
      bw[r] = *(const f32x4*)&sbeta[c * 16 + r * 4];
      gw[r] = *(const f32x4*)&sG[c * 16 + r * 4];
    }

    // ---- chunk preamble: u for step 0 = Sold . k_0  (Sold = S_{t0-2}) ----
    f32x2 k2cur[2];
    k2cur[0] = unpk(kw[0][0]);
    k2cur[1] = unpk(kw[0][1]);
    {
      f32x2 dd = Sold0 * k2cur[0];
      dd += Sold1 * k2cur[1];
      float un = dd[0] + dd[1];
      un += dpp_f<0xB1>(un);
      un += dpp_f<0x4E>(un);
      un += dpp_f<0x141>(un);
      un += dpp_f<0x140>(un);
      u = un;   // c==0: Sold=0 -> u=0, correct
    }

#pragma unroll
    for (int i = 0; i < 16; ++i) {
      float bt = bw[i >> 2][i & 3];
      float Gt = gw[i >> 2][i & 3];
      unsigned int wv = vw[i >> 3][(i >> 1) & 3];
      unsigned int wa = aw[i >> 3][(i >> 1) & 3];
      float vr = (i & 1) ? bcf(wv & 0xffff0000u) : bcf(wv << 16);
      float ar = (i & 1) ? bcf(wa & 0xffff0000u) : bcf(wa << 16);

      // u_{t+1} = S_{t-1}.k_{t+1}  (off-chain; full iteration of slack)
      float unxt = 0.f;
      f32x2 k2n[2];
      if (i < 15) {
        k2n[0] = unpk(kw[(i + 1) >> 1][((i + 1) & 1) * 2]);
        k2n[1] = unpk(kw[(i + 1) >> 1][((i + 1) & 1) * 2 + 1]);
        f32x2 dd = S2[0] * k2n[0];
        dd += S2[1] * k2n[1];
        unxt = dd[0] + dd[1];
        unxt += dpp_f<0xB1>(unxt);
        unxt += dpp_f<0x4E>(unxt);
        unxt += dpp_f<0x141>(unxt);
        unxt += dpp_f<0x140>(unxt);
      } else {
        Sold0 = S2[0]; Sold1 = S2[1];   // S_{t-1} for next chunk's preamble
      }

      // serial chain: cc_t = A_t - cc_{t-1} * G_t  (1 fma)
      float A = bt * __builtin_fmaf(aprev, u, -vr);
      cc = __builtin_fmaf(-cc, Gt, A);

      // S update + output (off-chain throughput)
      f32x2 q2[2];
      q2[0] = unpk(qw[i >> 1][(i & 1) * 2]);
      q2[1] = unpk(qw[i >> 1][(i & 1) * 2 + 1]);
      const f32x2 cc2 = {cc, cc}, arv = {ar, ar};
      f32x2 oo;
      {
        f32x2 t0 = cc2 * k2cur[0]; S2[0] = arv * S2[0] - t0; oo = S2[0] * q2[0];
        f32x2 t1 = cc2 * k2cur[1]; S2[1] = arv * S2[1] - t1; oo += S2[1] * q2[1];
      }
      so[i][lane] = oo[0] + oo[1];       // deferred output partial

      aprev = ar;
      if (i < 15) { k2cur[0] = k2n[0]; k2cur[1] = k2n[1]; u = unxt; }
    }

    // deferred output reduction + coalesced store (single wave: ds-ordered)
    {
      int st = lane >> 2, rr = lane & 3;      // 64 outputs: 16 steps x 4 rows
      float4 A0 = *(const float4*)&so[st][rr * 16];
      float4 A1 = *(const float4*)&so[st][rr * 16 + 4];
      float4 A2 = *(const float4*)&so[st][rr * 16 + 8];
      float4 A3 = *(const float4*)&so[st][rr * 16 + 12];
      float s = (((A0.x + A0.y) + (A0.z + A0.w)) + ((A1.x + A1.y) + (A1.z + A1.w)))
              + (((A2.x + A2.y) + (A2.z + A2.w)) + ((A3.x + A3.y) + (A3.z + A3.w)));
      so2[st][rr] = cvt_bf16(s);
    }
    if (lane < 16)
      *(bf16x4v*)((__bf16*)o + bva + (size_t)(c * 16 + lane) * 1024) =
          *(const bf16x4v*)&so2[lane][0];

    if (hasNext) commit(buf ^ 1);
    __syncthreads();
  }
}

// LayerNorm over DV=64 per (b,t,h) row, *ln_w+ln_b, *gate -> bf16
__global__ __launch_bounds__(256) void ln_gate_kernel(
    const bf16* __restrict__ o, const bf16* __restrict__ g,
    const float* __restrict__ lnw, const float* __restrict__ lnb,
    bf16* __restrict__ out)
{
  int row = blockIdx.x * 4 + (threadIdx.x >> 6);
  int lane = threadIdx.x & 63;
  size_t idx = (size_t)row * 64 + lane;
  float xv = (float)o[idx];
  float mu = xv;
#pragma unroll
  for (int s = 1; s < 64; s <<= 1) mu += __shfl_xor(mu, s);
  mu *= (1.f / 64.f);
  float d = xv - mu;
  float vv = d * d;
#pragma unroll
  for (int s = 1; s < 64; s <<= 1) vv += __shfl_xor(vv, s);
  vv *= (1.f / 64.f);
  float y = d * rsqrtf(vv + 1e-5f) * lnw[lane] + lnb[lane];
  y *= (float)g[idx];
  out[idx] = (bf16)y;
}

extern "C" void kernel_launch(void* const* d_in, const int* in_sizes, int n_in,
                              void* d_out, int out_size, void* d_ws, size_t ws_size,
                              hipStream_t stream)
{
  const float* x   = (const float*)d_in[0];
  const float* Wq  = (const float*)d_in[1];
  const float* Wk  = (const float*)d_in[2];
  const float* Wv  = (const float*)d_in[3];
  const float* Wa  = (const float*)d_in[4];
  const float* ba  = (const float*)d_in[5];
  const float* Wb  = (const float*)d_in[6];
  const float* bb  = (const float*)d_in[7];
  const float* Wg  = (const float*)d_in[8];
  const float* Wo  = (const float*)d_in[9];
  const float* qcw = (const float*)d_in[10];
  const float* qcb = (const float*)d_in[11];
  const float* kcw = (const float*)d_in[12];
  const float* kcb = (const float*)d_in[13];
  const float* vcw = (const float*)d_in[14];
  const float* vcb = (const float*)d_in[15];
  const float* lnw = (const float*)d_in[16];
  const float* lnb = (const float*)d_in[17];

  const int M = 4096, HID = 1024;
  const size_t PLANE = (size_t)M * HID;
  const size_t PB = PLANE * sizeof(bf16);          // 8 MB bf16 plane

  char* ws = (char*)d_ws;
  bf16* P  = (bf16*)(ws);            // z-plane x3, then a-gate
  bf16* qb = (bf16*)(ws + PB);       // q, then g-gate
  bf16* kb = (bf16*)(ws + 2 * PB);   // k, then normalized*gated o
  bf16* vb = (bf16*)(ws + 3 * PB);   // v

  // d_out scratch: betab [16][4096] fp32 at [0,256K); G at [256K,512K);
  // ob at [8M,16M). All dead before the final GEMM writes d_out.
  float* outf  = (float*)d_out;
  float* betab = outf;
  float* gkk   = (float*)((char*)d_out + 256 * 1024);
  bf16*  ob    = (bf16*)((char*)d_out + 8 * 1024 * 1024);

  const bool rich = (ws_size >= 5 * PB + 1024);
  bf16* xb = rich ? (bf16*)(ws + 4 * PB) : nullptr;

  dim3 blk(256);
  dim3 g8(8, 32);
  int nconv = (int)(PLANE / 256);

  if (rich) {
    cvt_plane_kernel<<<(int)(PLANE / 1024), blk, 0, stream>>>(x, xb);
    gemm_bt<2, false><<<g8, blk, 0, stream>>>(xb, Wq, nullptr, nullptr, P, M, HID, HID);
    conv_silu_kernel<<<nconv, blk, 0, stream>>>(P, qcw, qcb, qb, 1.f);
    gemm_bt<2, false><<<g8, blk, 0, stream>>>(xb, Wk, nullptr, nullptr, P, M, HID, HID);
    conv_silu_kernel<<<nconv, blk, 0, stream>>>(P, kcw, kcb, kb, 0.125f);
    gemm_bt<2, false><<<g8, blk, 0, stream>>>(xb, Wv, nullptr, nullptr, P, M, HID, HID);
    conv_silu_kernel<<<nconv, blk, 0, stream>>>(P, vcw, vcb, vb, 1.f);
    gemm_bt<3, false><<<g8, blk, 0, stream>>>(xb, Wa, ba, nullptr, P, M, HID, HID);
    gemm_bt<5, false><<<dim3(1, 32), blk, 0, stream>>>(xb, Wb, bb, betab, nullptr, M, 16, HID);
    kk_kernel<<<1024, blk, 0, stream>>>(kb, betab, gkk);
    scan_kernel<<<512, dim3(64), 0, stream>>>(qb, kb, vb, P, betab, gkk, ob);
    gemm_bt<3, false><<<g8, blk, 0, stream>>>(xb, Wg, nullptr, nullptr, qb, M, HID, HID);
    ln_gate_kernel<<<M * 16 / 4, blk, 0, stream>>>(ob, qb, lnw, lnb, kb);
  } else {
    gemm_bt<2, true><<<g8, blk, 0, stream>>>(x, Wq, nullptr, nullptr, P, M, HID, HID);
    conv_silu_kernel<<<nconv, blk, 0, stream>>>(P, qcw, qcb, qb, 1.f);
    gemm_bt<2, true><<<g8, blk, 0, stream>>>(x, Wk, nullptr, nullptr, P, M, HID, HID);
    conv_silu_kernel<<<nconv, blk, 0, stream>>>(P, kcw, kcb, kb, 0.125f);
    gemm_bt<2, true><<<g8, blk, 0, stream>>>(x, Wv, nullptr, nullptr, P, M, HID, HID);
    conv_silu_kernel<<<nconv, blk, 0, stream>>>(P, vcw, vcb, vb, 1.f);
    gemm_bt<3, true><<<g8, blk, 0, stream>>>(x, Wa, ba, nullptr, P, M, HID, HID);
    gemm_bt<5, true><<<dim3(1, 32), blk, 0, stream>>>(x, Wb, bb, betab, nullptr, M, 16, HID);
    kk_kernel<<<1024, blk, 0, stream>>>(kb, betab, gkk);
    scan_kernel<<<512, dim3(64), 0, stream>>>(qb, kb, vb, P, betab, gkk, ob);
    gemm_bt<3, true><<<g8, blk, 0, stream>>>(x, Wg, nullptr, nullptr, qb, M, HID, HID);
    ln_gate_kernel<<<M * 16 / 4, blk, 0, stream>>>(ob, qb, lnw, lnb, kb);
  }

  gemm_bt<4, false><<<g8, blk, 0, stream>>>(kb, Wo, nullptr, outf, nullptr, M, HID, HID);
}

// Round 4
// 610.458 us; speedup vs baseline: 1.0030x; 1.0030x over previous
//
#include <hip/hip_runtime.h>
#include <hip/hip_bf16.h>
#include <cstdint>

// B=2, T=2048, HID=1024, H=16, DK=DV=64, K(conv)=4. fp32 in/out.
// ws: 4 bf16 planes (32 MB) [+ optional 5th plane xb if ws_size >= 40 MB].
// d_out as scratch: betab fp32 transposed [16][4096] at [0,256K); G=beta*kk
// fp32 [16][4096] at [256K,512K); scan output plane ob bf16 at [8M,16M).
// All dead before the final GEMM writes d_out.
//
// Scan: 512 blocks x 64 thr; block owns 4 DV rows; 16 lanes/row.
// LOOK-AHEAD TRANSFORM: dot_t = a_{t-1}*u_t - cc_{t-1}*kk_t, u_t = S_{t-2}.k_t,
// G_t = beta_t*(k_{t-1}.k_t) precomputed -> serial chain = 1 fma/step.
// CHUNK-BULK LDS + SCHED_BARRIER PIN: all 16 steps' operands are loaded with
// ~28 ds_read_b128 at chunk start, then __builtin_amdgcn_sched_barrier(0)
// forbids the scheduler from re-sinking them into the loop (R2/R3 showed
// hipcc sinks them to minimize live ranges -> per-step LDS stalls; VGPR
// stayed 88). With the pin, operands are register-resident: ONE lgkmcnt
// wait per chunk. Verification signal: VGPR_Count must rise to ~160+.

using bf16 = __hip_bfloat16;
typedef __bf16 bf16x8 __attribute__((ext_vector_type(8)));
typedef __bf16 bf16x4v __attribute__((ext_vector_type(4)));
typedef float f32x4 __attribute__((ext_vector_type(4)));
typedef float f32x2 __attribute__((ext_vector_type(2)));
typedef unsigned int u32x4 __attribute__((ext_vector_type(4)));
typedef unsigned int u32x2 __attribute__((ext_vector_type(2)));

__device__ __forceinline__ __bf16 cvt_bf16(float f) {
  __hip_bfloat16 h = (__hip_bfloat16)f;
  return *reinterpret_cast<__bf16*>(&h);
}
__device__ __forceinline__ void async_copy16(const void* g, void* l) {
  __builtin_amdgcn_global_load_lds((const __attribute__((address_space(1))) void*)g,
                                   (__attribute__((address_space(3))) void*)l,
                                   16, 0, 0);
}
__device__ __forceinline__ float bcf(unsigned int u) { return __builtin_bit_cast(float, u); }
template <int CTRL>
__device__ __forceinline__ float dpp_f(float x) {
  int y = __builtin_amdgcn_update_dpp(0, __builtin_bit_cast(int, x), CTRL, 0xF, 0xF, true);
  return __builtin_bit_cast(float, y);
}

// fp32 -> bf16 plane (4M elements)
__global__ __launch_bounds__(256) void cvt_plane_kernel(
    const float* __restrict__ in, bf16* __restrict__ out)
{
  size_t i = ((size_t)blockIdx.x * 256 + threadIdx.x) * 4;
  float4 f = *(const float4*)(in + i);
  bf16x4v t;
  t[0] = cvt_bf16(f.x); t[1] = cvt_bf16(f.y); t[2] = cvt_bf16(f.z); t[3] = cvt_bf16(f.w);
  *(bf16x4v*)((__bf16*)out + i) = t;
}

// C = A * Bt^T. A: MxK (bf16 async-staged unless A_FP32); Bt: NxK fp32.
// MODE 2: raw->bf16; 3: sigmoid(acc+bias)->bf16; 4: raw->fp32; 5: sigmoid(acc+bias)->fp32 TRANSPOSED
template <int MODE, bool A_FP32>
__global__ __launch_bounds__(256) void gemm_bt(
    const void* __restrict__ Av, const float* __restrict__ Bt,
    const float* __restrict__ bias, float* __restrict__ Cf, bf16* __restrict__ Cb,
    int M, int N, int K)
{
  __shared__ __align__(16) __bf16 As[128 * 32];
  __shared__ __align__(16) __bf16 Bs[128 * 32];

  const int tid  = threadIdx.x;
  const int lane = tid & 63;
  const int wave = tid >> 6;
  const int tile_m = blockIdx.y * 128;
  const int tile_n = blockIdx.x * 128;
  const int wm = (wave >> 1) * 64;
  const int wn = (wave & 1) * 64;

  const int srow = lane >> 2;
  const int scol = (lane & 3) * 8;

  f32x4 acc[4][4];
#pragma unroll
  for (int i = 0; i < 4; ++i)
#pragma unroll
    for (int j = 0; j < 4; ++j) acc[i][j] = {0.f, 0.f, 0.f, 0.f};

  for (int k0 = 0; k0 < K; k0 += 32) {
    float4 b0[2], b1[2], a0[2], a1[2];
#pragma unroll
    for (int s = 0; s < 2; ++s) {
      int brow = tile_n + s * 64 + wave * 16 + srow;
      if (brow > N - 1) brow = N - 1;             // clamp (beta GEMM: N=16)
      const float* bp = Bt + (size_t)brow * K + k0 + scol;
      b0[s] = *(const float4*)bp;
      b1[s] = *(const float4*)(bp + 4);
      if (A_FP32) {
        int arow = tile_m + s * 64 + wave * 16 + srow;
        const float* ap = (const float*)Av + (size_t)arow * K + k0 + scol;
        a0[s] = *(const float4*)ap;
        a1[s] = *(const float4*)(ap + 4);
      }
    }
    __syncthreads();
#pragma unroll
    for (int s = 0; s < 2; ++s) {
      if (!A_FP32) {
        int arow = tile_m + s * 64 + wave * 16 + srow;
        async_copy16((const __bf16*)Av + (size_t)arow * K + k0 + scol,
                     &As[(s * 64 + wave * 16 + srow) * 32 + scol]);
      } else {
        bf16x8 ua;
        ua[0] = cvt_bf16(a0[s].x); ua[1] = cvt_bf16(a0[s].y);
        ua[2] = cvt_bf16(a0[s].z); ua[3] = cvt_bf16(a0[s].w);
        ua[4] = cvt_bf16(a1[s].x); ua[5] = cvt_bf16(a1[s].y);
        ua[6] = cvt_bf16(a1[s].z); ua[7] = cvt_bf16(a1[s].w);
        *(bf16x8*)&As[(s * 64 + wave * 16 + srow) * 32 + scol] = ua;
      }
      bf16x8 u;
      u[0] = cvt_bf16(b0[s].x); u[1] = cvt_bf16(b0[s].y);
      u[2] = cvt_bf16(b0[s].z); u[3] = cvt_bf16(b0[s].w);
      u[4] = cvt_bf16(b1[s].x); u[5] = cvt_bf16(b1[s].y);
      u[6] = cvt_bf16(b1[s].z); u[7] = cvt_bf16(b1[s].w);
      *(bf16x8*)&Bs[(s * 64 + wave * 16 + srow) * 32 + scol] = u;
    }
    __syncthreads();

    bf16x8 af[4], bfr[4];
#pragma unroll
    for (int i = 0; i < 4; ++i)
      af[i] = *(const bf16x8*)&As[(wm + i * 16 + (lane & 15)) * 32 + (lane >> 4) * 8];
#pragma unroll
    for (int j = 0; j < 4; ++j)
      bfr[j] = *(const bf16x8*)&Bs[(wn + j * 16 + (lane & 15)) * 32 + (lane >> 4) * 8];

#pragma unroll
    for (int i = 0; i < 4; ++i)
#pragma unroll
      for (int j = 0; j < 4; ++j)
        acc[i][j] = __builtin_amdgcn_mfma_f32_16x16x32_bf16(af[i], bfr[j], acc[i][j], 0, 0, 0);
  }

  // C/D layout (m89-verified): col = lane&15, row = (lane>>4)*4 + reg
#pragma unroll
  for (int i = 0; i < 4; ++i) {
#pragma unroll
    for (int j = 0; j < 4; ++j) {
#pragma unroll
      for (int r = 0; r < 4; ++r) {
        int gm = tile_m + wm + i * 16 + (lane >> 4) * 4 + r;
        int gn = tile_n + wn + j * 16 + (lane & 15);
        if (gn < N) {
          float val = acc[i][j][r];
          if (MODE == 3 || MODE == 5) {
            float bv = bias ? bias[gn] : 0.f;
            val = 1.f / (1.f + __expf(-(val + bv)));
          }
          if (MODE == 4)      Cf[(size_t)gm * N + gn] = val;
          else if (MODE == 5) Cf[(size_t)gn * M + gm] = val;   // transposed
          else                Cb[(size_t)gm * N + gn] = (bf16)val;
        }
      }
    }
  }
}

// causal depthwise conv K=4 + bias + SiLU (+scale). z: [B*T,1024] bf16 plane.
__global__ __launch_bounds__(256) void conv_silu_kernel(
    const bf16* __restrict__ z, const float* __restrict__ w,
    const float* __restrict__ bias, bf16* __restrict__ out, float scale)
{
  int idx = blockIdx.x * 256 + threadIdx.x;
  int c = idx & 1023;
  int m = idx >> 10;
  int t = m & 2047;
  float w0 = w[c * 4 + 0], w1 = w[c * 4 + 1], w2 = w[c * 4 + 2], w3 = w[c * 4 + 3];
  float acc = bias[c] + (float)z[idx] * w3;
  if (t >= 1) acc += (float)z[idx - 1024] * w2;
  if (t >= 2) acc += (float)z[idx - 2048] * w1;
  if (t >= 3) acc += (float)z[idx - 3072] * w0;
  float s = acc / (1.f + __expf(-acc));
  out[idx] = (bf16)(s * scale);
}

// G[h][b*2048+t] = beta[h][b*2048+t] * (k_{t-1} . k_t) over DK=64 (0 at t=0).
__global__ __launch_bounds__(256) void kk_kernel(
    const bf16* __restrict__ k, const float* __restrict__ betab,
    float* __restrict__ G)
{
  int tid = blockIdx.x * 256 + threadIdx.x;
  int out = tid >> 2;            // h*4096 + m, m = b*2048+t
  int j   = tid & 3;
  int h = out >> 12;
  int m = out & 4095;
  int t = m & 2047;
  float s = 0.f;
  if (t > 0) {
    const __bf16* r1 = (const __bf16*)k + (size_t)m * 1024 + h * 64 + j * 16;
    const __bf16* r0 = r1 - 1024;
    bf16x8 a0 = *(const bf16x8*)r0;
    bf16x8 a1 = *(const bf16x8*)(r0 + 8);
    bf16x8 b0 = *(const bf16x8*)r1;
    bf16x8 b1 = *(const bf16x8*)(r1 + 8);
#pragma unroll
    for (int e = 0; e < 8; ++e)
      s += (float)a0[e] * (float)b0[e] + (float)a1[e] * (float)b1[e];
  }
  s += __shfl_xor(s, 1);
  s += __shfl_xor(s, 2);
  if (j == 0) G[out] = betab[out] * s;
}

// delta-rule scan with look-ahead + chunk-bulk register operands, pinned.
// 512 blocks (b,h,qd) x 64 thr; block owns DV rows [qd*4, qd*4+4).
// Lane (r4=lane>>4, sg=lane&15) holds S[r4][sg*4..+4) fp32.
__global__ __launch_bounds__(64, 1) void scan_kernel(
    const bf16* __restrict__ q, const bf16* __restrict__ k,
    const bf16* __restrict__ v, const bf16* __restrict__ a,
    const float* __restrict__ betab, const float* __restrict__ gkk,
    bf16* __restrict__ o)
{
  const int blk = blockIdx.x;
  const int qd = blk >> 5;           // DV slice 0..15 (4 rows each)
  const int bh = blk & 31;
  const int b = bh >> 4, h = bh & 15;
  const int lane = threadIdx.x;      // single wave
  const int r4 = lane >> 4;          // local row 0..3
  const int sg = lane & 15;

  // transposed chunk staging: [sg][18 slots of 4 bf16] (144B stride)
  __shared__ __align__(16) __bf16 skT[2][16][72];    // 4608 B
  __shared__ __align__(16) __bf16 sqT[2][16][72];    // 4608 B
  __shared__ __align__(16) __bf16 svaT[2][2][4][16]; // 512 B [buf][v/a][row][step]
  __shared__ __align__(16) float  so[16][68];        // 4352 B (balanced banks)
  __shared__ __align__(16) __bf16 so2[16][4];        // reduced outputs
  __shared__ float sbeta[2048];                      // 8 KB
  __shared__ float sG[2048];                         // 8 KB  beta*kk

  {
    const float* bp = betab + (size_t)h * 4096 + b * 2048;
    const float* gp = gkk   + (size_t)h * 4096 + b * 2048;
    for (int t = lane; t < 2048; t += 64) { sbeta[t] = bp[t]; sG[t] = gp[t]; }
  }

  const size_t bkq = (size_t)b * 2048 * 1024 + h * 64;   // k/q plane base
  const size_t bva = bkq + qd * 4;                       // v/a/o slice base
  const __bf16* kp = (const __bf16*)k;
  const __bf16* qp = (const __bf16*)q;

  const int g_st = lane >> 3;          // staging step-in-group 0..7
  const int g_cg = (lane & 7) * 8;     // staging col (bf16 units)
  const int sgp  = (lane & 7) * 2;     // sg-slice pair base for commit
  const int va_vh = (lane >> 4) & 1;   // lanes 0-15: v, 16-31: a
  const int va_st = lane & 15;

  bf16x8 pk[2], pq[2];
  bf16x4v pva;
  auto fetch = [&](int t0) {
#pragma unroll
    for (int j = 0; j < 2; ++j) {
      int st = t0 + j * 8 + g_st;
      pk[j] = *(const bf16x8*)(kp + bkq + (size_t)st * 1024 + g_cg);
      pq[j] = *(const bf16x8*)(qp + bkq + (size_t)st * 1024 + g_cg);
    }
    if (lane < 32) {
      const __bf16* src = va_vh ? (const __bf16*)a : (const __bf16*)v;
      pva = *(const bf16x4v*)(src + bva + (size_t)(t0 + va_st) * 1024);
    }
  };
  auto commit = [&](int cb) {
#pragma unroll
    for (int j = 0; j < 2; ++j) {
      int stl = j * 8 + g_st;          // step in chunk 0..15
      u32x4 wk = __builtin_bit_cast(u32x4, pk[j]);
      u32x4 wq = __builtin_bit_cast(u32x4, pq[j]);
      u32x2 lo, hi;
      lo[0] = wk[0]; lo[1] = wk[1]; hi[0] = wk[2]; hi[1] = wk[3];
      *(u32x2*)&skT[cb][sgp][stl * 4]     = lo;
      *(u32x2*)&skT[cb][sgp + 1][stl * 4] = hi;
      lo[0] = wq[0]; lo[1] = wq[1]; hi[0] = wq[2]; hi[1] = wq[3];
      *(u32x2*)&sqT[cb][sgp][stl * 4]     = lo;
      *(u32x2*)&sqT[cb][sgp + 1][stl * 4] = hi;
    }
    if (lane < 32) {
#pragma unroll
      for (int r = 0; r < 4; ++r) svaT[cb][va_vh][r][va_st] = pva[r];
    }
  };

  fetch(0); commit(0);

  f32x2 S2[2];
  S2[0] = {0.f, 0.f}; S2[1] = {0.f, 0.f};
  f32x2 Sold0 = {0.f, 0.f}, Sold1 = {0.f, 0.f};
  float u = 0.f, cc = 0.f, aprev = 0.f;
  __syncthreads();

  auto unpk = [&](unsigned int w) -> f32x2 {
    f32x2 r; r[0] = bcf(w << 16); r[1] = bcf(w & 0xffff0000u); return r;
  };

  for (int c = 0; c < 128; ++c) {
    const int buf = c & 1;
    const bool hasNext = (c + 1 < 128);

    if (hasNext) fetch((c + 1) * 16);   // issue VMEM before the lgkm wait below

    // ---- bulk LDS -> reg: one wait per chunk ----
    u32x4 kw[8], qw[8], vw[2], aw[2];
#pragma unroll
    for (int r = 0; r < 8; ++r) {
      kw[r] = *(const u32x4*)&skT[buf][sg][r * 8];
      qw[r] = *(const u32x4*)&sqT[buf][sg][r * 8];
    }
    vw[0] = *(const u32x4*)&svaT[buf][0][r4][0];
    vw[1] = *(const u32x4*)&svaT[buf][0][r4][8];
    aw[0] = *(const u32x4*)&svaT[buf][1][r4][0];
    aw[1] = *(const u32x4*)&svaT[buf][1][r4][8];
    f32x4 bw[4], gw[4];
#pragma unroll
    for (int r = 0; r < 4; ++r) {
      bw[r] = *(const f32x4*)&sbeta[c * 16 + r * 4];
      gw[r] = *(const f32x4*)&sG[c * 16 + r * 4];
    }
    // PIN: forbid the scheduler from sinking the above loads into the loop
    // (R2/R3: without this, hipcc re-sinks to minimize live ranges and every
    // step eats a raw dependent-LDS stall at 0.5 waves/SIMD).
    __builtin_amdgcn_sched_barrier(0);

    // ---- chunk preamble: u for step 0 = Sold . k_0  (Sold = S_{t0-2}) ----
    f32x2 k2cur[2];
    k2cur[0] = unpk(kw[0][0]);
    k2cur[1] = unpk(kw[0][1]);
    {
      f32x2 dd = Sold0 * k2cur[0];
      dd += Sold1 * k2cur[1];
      float un = dd[0] + dd[1];
      un += dpp_f<0xB1>(un);
      un += dpp_f<0x4E>(un);
      un += dpp_f<0x141>(un);
      un += dpp_f<0x140>(un);
      u = un;   // c==0: Sold=0 -> u=0, correct
    }

#pragma unroll
    for (int i = 0; i < 16; ++i) {
      float bt = bw[i >> 2][i & 3];
      float Gt = gw[i >> 2][i & 3];
      unsigned int wv = vw[i >> 3][(i >> 1) & 3];
      unsigned int wa = aw[i >> 3][(i >> 1) & 3];
      float vr = (i & 1) ? bcf(wv & 0xffff0000u) : bcf(wv << 16);
      float ar = (i & 1) ? bcf(wa & 0xffff0000u) : bcf(wa << 16);

      // u_{t+1} = S_{t-1}.k_{t+1}  (off-chain; full iteration of slack)
      float unxt = 0.f;
      f32x2 k2n[2];
      if (i < 15) {
        k2n[0] = unpk(kw[(i + 1) >> 1][((i + 1) & 1) * 2]);
        k2n[1] = unpk(kw[(i + 1) >> 1][((i + 1) & 1) * 2 + 1]);
        f32x2 dd = S2[0] * k2n[0];
        dd += S2[1] * k2n[1];
        unxt = dd[0] + dd[1];
        unxt += dpp_f<0xB1>(unxt);
        unxt += dpp_f<0x4E>(unxt);
        unxt += dpp_f<0x141>(unxt);
        unxt += dpp_f<0x140>(unxt);
      } else {
        Sold0 = S2[0]; Sold1 = S2[1];   // S_{t-1} for next chunk's preamble
      }

      // serial chain: cc_t = A_t - cc_{t-1} * G_t  (1 fma)
      float A = bt * __builtin_fmaf(aprev, u, -vr);
      cc = __builtin_fmaf(-cc, Gt, A);

      // S update + output (off-chain throughput)
      f32x2 q2[2];
      q2[0] = unpk(qw[i >> 1][(i & 1) * 2]);
      q2[1] = unpk(qw[i >> 1][(i & 1) * 2 + 1]);
      const f32x2 cc2 = {cc, cc}, arv = {ar, ar};
      f32x2 oo;
      {
        f32x2 t0 = cc2 * k2cur[0]; S2[0] = arv * S2[0] - t0; oo = S2[0] * q2[0];
        f32x2 t1 = cc2 * k2cur[1]; S2[1] = arv * S2[1] - t1; oo += S2[1] * q2[1];
      }
      so[i][lane] = oo[0] + oo[1];       // deferred output partial

      aprev = ar;
      if (i < 15) { k2cur[0] = k2n[0]; k2cur[1] = k2n[1]; u = unxt; }
    }
    __builtin_amdgcn_sched_barrier(0);   // keep chunk tail out of the loop

    // deferred output reduction + coalesced store (single wave: ds-ordered)
    {
      int st = lane >> 2, rr = lane & 3;      // 64 outputs: 16 steps x 4 rows
      float4 A0 = *(const float4*)&so[st][rr * 16];
      float4 A1 = *(const float4*)&so[st][rr * 16 + 4];
      float4 A2 = *(const float4*)&so[st][rr * 16 + 8];
      float4 A3 = *(const float4*)&so[st][rr * 16 + 12];
      float s = (((A0.x + A0.y) + (A0.z + A0.w)) + ((A1.x + A1.y) + (A1.z + A1.w)))
              + (((A2.x + A2.y) + (A2.z + A2.w)) + ((A3.x + A3.y) + (A3.z + A3.w)));
      so2[st][rr] = cvt_bf16(s);
    }
    if (lane < 16)
      *(bf16x4v*)((__bf16*)o + bva + (size_t)(c * 16 + lane) * 1024) =
          *(const bf16x4v*)&so2[lane][0];

    if (hasNext) commit(buf ^ 1);
    __syncthreads();
  }
}

// LayerNorm over DV=64 per (b,t,h) row, *ln_w+ln_b, *gate -> bf16
__global__ __launch_bounds__(256) void ln_gate_kernel(
    const bf16* __restrict__ o, const bf16* __restrict__ g,
    const float* __restrict__ lnw, const float* __restrict__ lnb,
    bf16* __restrict__ out)
{
  int row = blockIdx.x * 4 + (threadIdx.x >> 6);
  int lane = threadIdx.x & 63;
  size_t idx = (size_t)row * 64 + lane;
  float xv = (float)o[idx];
  float mu = xv;
#pragma unroll
  for (int s = 1; s < 64; s <<= 1) mu += __shfl_xor(mu, s);
  mu *= (1.f / 64.f);
  float d = xv - mu;
  float vv = d * d;
#pragma unroll
  for (int s = 1; s < 64; s <<= 1) vv += __shfl_xor(vv, s);
  vv *= (1.f / 64.f);
  float y = d * rsqrtf(vv + 1e-5f) * lnw[lane] + lnb[lane];
  y *= (float)g[idx];
  out[idx] = (bf16)y;
}

extern "C" void kernel_launch(void* const* d_in, const int* in_sizes, int n_in,
                              void* d_out, int out_size, void* d_ws, size_t ws_size,
                              hipStream_t stream)
{
  const float* x   = (const float*)d_in[0];
  const float* Wq  = (const float*)d_in[1];
  const float* Wk  = (const float*)d_in[2];
  const float* Wv  = (const float*)d_in[3];
  const float* Wa  = (const float*)d_in[4];
  const float* ba  = (const float*)d_in[5];
  const float* Wb  = (const float*)d_in[6];
  const float* bb  = (const float*)d_in[7];
  const float* Wg  = (const float*)d_in[8];
  const float* Wo  = (const float*)d_in[9];
  const float* qcw = (const float*)d_in[10];
  const float* qcb = (const float*)d_in[11];
  const float* kcw = (const float*)d_in[12];
  const float* kcb = (const float*)d_in[13];
  const float* vcw = (const float*)d_in[14];
  const float* vcb = (const float*)d_in[15];
  const float* lnw = (const float*)d_in[16];
  const float* lnb = (const float*)d_in[17];

  const int M = 4096, HID = 1024;
  const size_t PLANE = (size_t)M * HID;
  const size_t PB = PLANE * sizeof(bf16);          // 8 MB bf16 plane

  char* ws = (char*)d_ws;
  bf16* P  = (bf16*)(ws);            // z-plane x3, then a-gate
  bf16* qb = (bf16*)(ws + PB);       // q, then g-gate
  bf16* kb = (bf16*)(ws + 2 * PB);   // k, then normalized*gated o
  bf16* vb = (bf16*)(ws + 3 * PB);   // v

  // d_out scratch: betab [16][4096] fp32 at [0,256K); G at [256K,512K);
  // ob at [8M,16M). All dead before the final GEMM writes d_out.
  float* outf  = (float*)d_out;
  float* betab = outf;
  float* gkk   = (float*)((char*)d_out + 256 * 1024);
  bf16*  ob    = (bf16*)((char*)d_out + 8 * 1024 * 1024);

  const bool rich = (ws_size >= 5 * PB + 1024);
  bf16* xb = rich ? (bf16*)(ws + 4 * PB) : nullptr;

  dim3 blk(256);
  dim3 g8(8, 32);
  int nconv = (int)(PLANE / 256);

  if (rich) {
    cvt_plane_kernel<<<(int)(PLANE / 1024), blk, 0, stream>>>(x, xb);
    gemm_bt<2, false><<<g8, blk, 0, stream>>>(xb, Wq, nullptr, nullptr, P, M, HID, HID);
    conv_silu_kernel<<<nconv, blk, 0, stream>>>(P, qcw, qcb, qb, 1.f);
    gemm_bt<2, false><<<g8, blk, 0, stream>>>(xb, Wk, nullptr, nullptr, P, M, HID, HID);
    conv_silu_kernel<<<nconv, blk, 0, stream>>>(P, kcw, kcb, kb, 0.125f);
    gemm_bt<2, false><<<g8, blk, 0, stream>>>(xb, Wv, nullptr, nullptr, P, M, HID, HID);
    conv_silu_kernel<<<nconv, blk, 0, stream>>>(P, vcw, vcb, vb, 1.f);
    gemm_bt<3, false><<<g8, blk, 0, stream>>>(xb, Wa, ba, nullptr, P, M, HID, HID);
    gemm_bt<5, false><<<dim3(1, 32), blk, 0, stream>>>(xb, Wb, bb, betab, nullptr, M, 16, HID);
    kk_kernel<<<1024, blk, 0, stream>>>(kb, betab, gkk);
    scan_kernel<<<512, dim3(64), 0, stream>>>(qb, kb, vb, P, betab, gkk, ob);
    gemm_bt<3, false><<<g8, blk, 0, stream>>>(xb, Wg, nullptr, nullptr, qb, M, HID, HID);
    ln_gate_kernel<<<M * 16 / 4, blk, 0, stream>>>(ob, qb, lnw, lnb, kb);
  } else {
    gemm_bt<2, true><<<g8, blk, 0, stream>>>(x, Wq, nullptr, nullptr, P, M, HID, HID);
    conv_silu_kernel<<<nconv, blk, 0, stream>>>(P, qcw, qcb, qb, 1.f);
    gemm_bt<2, true><<<g8, blk, 0, stream>>>(x, Wk, nullptr, nullptr, P, M, HID, HID);
    conv_silu_kernel<<<nconv, blk, 0, stream>>>(P, kcw, kcb, kb, 0.125f);
    gemm_bt<2, true><<<g8, blk, 0, stream>>>(x, Wv, nullptr, nullptr, P, M, HID, HID);
    conv_silu_kernel<<<nconv, blk, 0, stream>>>(P, vcw, vcb, vb, 1.f);
    gemm_bt<3, true><<<g8, blk, 0, stream>>>(x, Wa, ba, nullptr, P, M, HID, HID);
    gemm_bt<5, true><<<dim3(1, 32), blk, 0, stream>>>(x, Wb, bb, betab, nullptr, M, 16, HID);
    kk_kernel<<<1024, blk, 0, stream>>>(kb, betab, gkk);
    scan_kernel<<<512, dim3(64), 0, stream>>>(qb, kb, vb, P, betab, gkk, ob);
    gemm_bt<3, true><<<g8, blk, 0, stream>>>(x, Wg, nullptr, nullptr, qb, M, HID, HID);
    ln_gate_kernel<<<M * 16 / 4, blk, 0, stream>>>(ob, qb, lnw, lnb, kb);
  }

  gemm_bt<4, false><<<g8, blk, 0, stream>>>(kb, Wo, nullptr, outf, nullptr, M, HID, HID);
}

// Round 5
// 553.597 us; speedup vs baseline: 1.1060x; 1.1027x over previous
//
#include <hip/hip_runtime.h>
#include <hip/hip_bf16.h>
#include <cstdint>

// B=2, T=2048, HID=1024, H=16, DK=DV=64, K(conv)=4. fp32 in/out.
// RICH layout (ws >= 40MB): ws = 5 bf16 planes P0..P4 (8 MB each).
//   d_out scratch: xb bf16 [0,8M) (dead after g/beta GEMMs);
//   betab fp32 [16][4096] at [0,256K) (over dead xb rows, write-after-read
//   safe within beta-GEMM block 0); G at [256K,512K); ob bf16 at [8M,16M).
// Pipeline: cvt -> mega_gemm(zq,zk,zv,a) -> conv q/k/v (plane rotation)
//   -> g-GEMM -> beta-GEMM -> kk -> scan -> ln_gate -> final GEMM.
// mega_gemm: 4 projections fused, grid 32x32=1024 blocks (4/CU) for
// inter-block barrier overlap + x L2 reuse (vs 4x 256-block GEMMs at 1/CU).
//
// Scan: look-ahead transform (serial chain = 1 fma/step) + chunk-bulk LDS
// with ASM REGISTER PIN: empty `asm volatile` with "+v" on all staged values
// forces materialization of the 28 ds_read_b128 at chunk start (sched_barrier
// failed in R3/R4 -- sinking happens at IR level; "+v" is semantically
// binding). Verification: scan VGPR_Count must rise ~88 -> ~200.

using bf16 = __hip_bfloat16;
typedef __bf16 bf16x8 __attribute__((ext_vector_type(8)));
typedef __bf16 bf16x4v __attribute__((ext_vector_type(4)));
typedef float f32x4 __attribute__((ext_vector_type(4)));
typedef float f32x2 __attribute__((ext_vector_type(2)));
typedef unsigned int u32x4 __attribute__((ext_vector_type(4)));
typedef unsigned int u32x2 __attribute__((ext_vector_type(2)));

__device__ __forceinline__ __bf16 cvt_bf16(float f) {
  __hip_bfloat16 h = (__hip_bfloat16)f;
  return *reinterpret_cast<__bf16*>(&h);
}
__device__ __forceinline__ void async_copy16(const void* g, void* l) {
  __builtin_amdgcn_global_load_lds((const __attribute__((address_space(1))) void*)g,
                                   (__attribute__((address_space(3))) void*)l,
                                   16, 0, 0);
}
__device__ __forceinline__ float bcf(unsigned int u) { return __builtin_bit_cast(float, u); }
template <int CTRL>
__device__ __forceinline__ float dpp_f(float x) {
  int y = __builtin_amdgcn_update_dpp(0, __builtin_bit_cast(int, x), CTRL, 0xF, 0xF, true);
  return __builtin_bit_cast(float, y);
}

// fp32 -> bf16 plane (4M elements)
__global__ __launch_bounds__(256) void cvt_plane_kernel(
    const float* __restrict__ in, bf16* __restrict__ out)
{
  size_t i = ((size_t)blockIdx.x * 256 + threadIdx.x) * 4;
  float4 f = *(const float4*)(in + i);
  bf16x4v t;
  t[0] = cvt_bf16(f.x); t[1] = cvt_bf16(f.y); t[2] = cvt_bf16(f.z); t[3] = cvt_bf16(f.w);
  *(bf16x4v*)((__bf16*)out + i) = t;
}

// C = A * Bt^T. A: MxK (bf16 async-staged unless A_FP32); Bt: NxK fp32.
// MODE 2: raw->bf16; 3: sigmoid(acc+bias)->bf16; 4: raw->fp32; 5: sigmoid(acc+bias)->fp32 TRANSPOSED
template <int MODE, bool A_FP32>
__global__ __launch_bounds__(256) void gemm_bt(
    const void* __restrict__ Av, const float* __restrict__ Bt,
    const float* __restrict__ bias, float* __restrict__ Cf, bf16* __restrict__ Cb,
    int M, int N, int K)
{
  __shared__ __align__(16) __bf16 As[128 * 32];
  __shared__ __align__(16) __bf16 Bs[128 * 32];

  const int tid  = threadIdx.x;
  const int lane = tid & 63;
  const int wave = tid >> 6;
  const int tile_m = blockIdx.y * 128;
  const int tile_n = blockIdx.x * 128;
  const int wm = (wave >> 1) * 64;
  const int wn = (wave & 1) * 64;

  const int srow = lane >> 2;
  const int scol = (lane & 3) * 8;

  f32x4 acc[4][4];
#pragma unroll
  for (int i = 0; i < 4; ++i)
#pragma unroll
    for (int j = 0; j < 4; ++j) acc[i][j] = {0.f, 0.f, 0.f, 0.f};

  for (int k0 = 0; k0 < K; k0 += 32) {
    float4 b0[2], b1[2], a0[2], a1[2];
#pragma unroll
    for (int s = 0; s < 2; ++s) {
      int brow = tile_n + s * 64 + wave * 16 + srow;
      if (brow > N - 1) brow = N - 1;             // clamp (beta GEMM: N=16)
      const float* bp = Bt + (size_t)brow * K + k0 + scol;
      b0[s] = *(const float4*)bp;
      b1[s] = *(const float4*)(bp + 4);
      if (A_FP32) {
        int arow = tile_m + s * 64 + wave * 16 + srow;
        const float* ap = (const float*)Av + (size_t)arow * K + k0 + scol;
        a0[s] = *(const float4*)ap;
        a1[s] = *(const float4*)(ap + 4);
      }
    }
    __syncthreads();
#pragma unroll
    for (int s = 0; s < 2; ++s) {
      if (!A_FP32) {
        int arow = tile_m + s * 64 + wave * 16 + srow;
        async_copy16((const __bf16*)Av + (size_t)arow * K + k0 + scol,
                     &As[(s * 64 + wave * 16 + srow) * 32 + scol]);
      } else {
        bf16x8 ua;
        ua[0] = cvt_bf16(a0[s].x); ua[1] = cvt_bf16(a0[s].y);
        ua[2] = cvt_bf16(a0[s].z); ua[3] = cvt_bf16(a0[s].w);
        ua[4] = cvt_bf16(a1[s].x); ua[5] = cvt_bf16(a1[s].y);
        ua[6] = cvt_bf16(a1[s].z); ua[7] = cvt_bf16(a1[s].w);
        *(bf16x8*)&As[(s * 64 + wave * 16 + srow) * 32 + scol] = ua;
      }
      bf16x8 u;
      u[0] = cvt_bf16(b0[s].x); u[1] = cvt_bf16(b0[s].y);
      u[2] = cvt_bf16(b0[s].z); u[3] = cvt_bf16(b0[s].w);
      u[4] = cvt_bf16(b1[s].x); u[5] = cvt_bf16(b1[s].y);
      u[6] = cvt_bf16(b1[s].z); u[7] = cvt_bf16(b1[s].w);
      *(bf16x8*)&Bs[(s * 64 + wave * 16 + srow) * 32 + scol] = u;
    }
    __syncthreads();

    bf16x8 af[4], bfr[4];
#pragma unroll
    for (int i = 0; i < 4; ++i)
      af[i] = *(const bf16x8*)&As[(wm + i * 16 + (lane & 15)) * 32 + (lane >> 4) * 8];
#pragma unroll
    for (int j = 0; j < 4; ++j)
      bfr[j] = *(const bf16x8*)&Bs[(wn + j * 16 + (lane & 15)) * 32 + (lane >> 4) * 8];

#pragma unroll
    for (int i = 0; i < 4; ++i)
#pragma unroll
      for (int j = 0; j < 4; ++j)
        acc[i][j] = __builtin_amdgcn_mfma_f32_16x16x32_bf16(af[i], bfr[j], acc[i][j], 0, 0, 0);
  }

  // C/D layout (m89-verified): col = lane&15, row = (lane>>4)*4 + reg
#pragma unroll
  for (int i = 0; i < 4; ++i) {
#pragma unroll
    for (int j = 0; j < 4; ++j) {
#pragma unroll
      for (int r = 0; r < 4; ++r) {
        int gm = tile_m + wm + i * 16 + (lane >> 4) * 4 + r;
        int gn = tile_n + wn + j * 16 + (lane & 15);
        if (gn < N) {
          float val = acc[i][j][r];
          if (MODE == 3 || MODE == 5) {
            float bv = bias ? bias[gn] : 0.f;
            val = 1.f / (1.f + __expf(-(val + bv)));
          }
          if (MODE == 4)      Cf[(size_t)gm * N + gn] = val;
          else if (MODE == 5) Cf[(size_t)gn * M + gm] = val;   // transposed
          else                Cb[(size_t)gm * N + gn] = (bf16)val;
        }
      }
    }
  }
}

// Fused 4-projection GEMM: C4 = A @ [Wq;Wk;Wv;Wa]^T, logical N=4096.
// Output: 4 contiguous bf16 planes at C4 (plane = gn>>10). Plane 3 (Wa):
// sigmoid(val + ba[col]). Grid (32,32) = 1024 blocks = 4/CU.
__global__ __launch_bounds__(256) void mega_gemm(
    const bf16* __restrict__ Av, const float* __restrict__ Wq,
    const float* __restrict__ Wk, const float* __restrict__ Wv,
    const float* __restrict__ Wa, const float* __restrict__ ba,
    bf16* __restrict__ C4, int M, int K)
{
  __shared__ __align__(16) __bf16 As[128 * 32];
  __shared__ __align__(16) __bf16 Bs[128 * 32];

  const int tid  = threadIdx.x;
  const int lane = tid & 63;
  const int wave = tid >> 6;
  const int tile_m = blockIdx.y * 128;
  const int tile_n = blockIdx.x * 128;
  const int grp = tile_n >> 10;                 // which weight (tile fully inside)
  const int tnl = tile_n & 1023;                // local col base
  const float* Bt = (grp == 0) ? Wq : (grp == 1) ? Wk : (grp == 2) ? Wv : Wa;
  const int wm = (wave >> 1) * 64;
  const int wn = (wave & 1) * 64;

  const int srow = lane >> 2;
  const int scol = (lane & 3) * 8;

  f32x4 acc[4][4];
#pragma unroll
  for (int i = 0; i < 4; ++i)
#pragma unroll
    for (int j = 0; j < 4; ++j) acc[i][j] = {0.f, 0.f, 0.f, 0.f};

  for (int k0 = 0; k0 < K; k0 += 32) {
    float4 b0[2], b1[2];
#pragma unroll
    for (int s = 0; s < 2; ++s) {
      int brow = tnl + s * 64 + wave * 16 + srow;
      const float* bp = Bt + (size_t)brow * K + k0 + scol;
      b0[s] = *(const float4*)bp;
      b1[s] = *(const float4*)(bp + 4);
    }
    __syncthreads();
#pragma unroll
    for (int s = 0; s < 2; ++s) {
      int arow = tile_m + s * 64 + wave * 16 + srow;
      async_copy16((const __bf16*)Av + (size_t)arow * K + k0 + scol,
                   &As[(s * 64 + wave * 16 + srow) * 32 + scol]);
      bf16x8 u;
      u[0] = cvt_bf16(b0[s].x); u[1] = cvt_bf16(b0[s].y);
      u[2] = cvt_bf16(b0[s].z); u[3] = cvt_bf16(b0[s].w);
      u[4] = cvt_bf16(b1[s].x); u[5] = cvt_bf16(b1[s].y);
      u[6] = cvt_bf16(b1[s].z); u[7] = cvt_bf16(b1[s].w);
      *(bf16x8*)&Bs[(s * 64 + wave * 16 + srow) * 32 + scol] = u;
    }
    __syncthreads();

    bf16x8 af[4], bfr[4];
#pragma unroll
    for (int i = 0; i < 4; ++i)
      af[i] = *(const bf16x8*)&As[(wm + i * 16 + (lane & 15)) * 32 + (lane >> 4) * 8];
#pragma unroll
    for (int j = 0; j < 4; ++j)
      bfr[j] = *(const bf16x8*)&Bs[(wn + j * 16 + (lane & 15)) * 32 + (lane >> 4) * 8];

#pragma unroll
    for (int i = 0; i < 4; ++i)
#pragma unroll
      for (int j = 0; j < 4; ++j)
        acc[i][j] = __builtin_amdgcn_mfma_f32_16x16x32_bf16(af[i], bfr[j], acc[i][j], 0, 0, 0);
  }

  bf16* Cp = C4 ? (bf16*)((__bf16*)C4 + (size_t)grp * M * 1024) : nullptr;
#pragma unroll
  for (int i = 0; i < 4; ++i) {
#pragma unroll
    for (int j = 0; j < 4; ++j) {
#pragma unroll
      for (int r = 0; r < 4; ++r) {
        int gm = tile_m + wm + i * 16 + (lane >> 4) * 4 + r;
        int col = tnl + wn + j * 16 + (lane & 15);
        float val = acc[i][j][r];
        if (grp == 3) val = 1.f / (1.f + __expf(-(val + ba[col])));
        ((__bf16*)Cp)[(size_t)gm * 1024 + col] = cvt_bf16(val);
      }
    }
  }
}

// causal depthwise conv K=4 + bias + SiLU (+scale). z: [B*T,1024] bf16 plane.
__global__ __launch_bounds__(256) void conv_silu_kernel(
    const bf16* __restrict__ z, const float* __restrict__ w,
    const float* __restrict__ bias, bf16* __restrict__ out, float scale)
{
  int idx = blockIdx.x * 256 + threadIdx.x;
  int c = idx & 1023;
  int m = idx >> 10;
  int t = m & 2047;
  float w0 = w[c * 4 + 0], w1 = w[c * 4 + 1], w2 = w[c * 4 + 2], w3 = w[c * 4 + 3];
  float acc = bias[c] + (float)z[idx] * w3;
  if (t >= 1) acc += (float)z[idx - 1024] * w2;
  if (t >= 2) acc += (float)z[idx - 2048] * w1;
  if (t >= 3) acc += (float)z[idx - 3072] * w0;
  float s = acc / (1.f + __expf(-acc));
  out[idx] = (bf16)(s * scale);
}

// G[h][b*2048+t] = beta[h][b*2048+t] * (k_{t-1} . k_t) over DK=64 (0 at t=0).
__global__ __launch_bounds__(256) void kk_kernel(
    const bf16* __restrict__ k, const float* __restrict__ betab,
    float* __restrict__ G)
{
  int tid = blockIdx.x * 256 + threadIdx.x;
  int out = tid >> 2;            // h*4096 + m, m = b*2048+t
  int j   = tid & 3;
  int h = out >> 12;
  int m = out & 4095;
  int t = m & 2047;
  float s = 0.f;
  if (t > 0) {
    const __bf16* r1 = (const __bf16*)k + (size_t)m * 1024 + h * 64 + j * 16;
    const __bf16* r0 = r1 - 1024;
    bf16x8 a0 = *(const bf16x8*)r0;
    bf16x8 a1 = *(const bf16x8*)(r0 + 8);
    bf16x8 b0 = *(const bf16x8*)r1;
    bf16x8 b1 = *(const bf16x8*)(r1 + 8);
#pragma unroll
    for (int e = 0; e < 8; ++e)
      s += (float)a0[e] * (float)b0[e] + (float)a1[e] * (float)b1[e];
  }
  s += __shfl_xor(s, 1);
  s += __shfl_xor(s, 2);
  if (j == 0) G[out] = betab[out] * s;
}

// delta-rule scan with look-ahead + chunk-bulk register operands, asm-pinned.
// 512 blocks (b,h,qd) x 64 thr; block owns DV rows [qd*4, qd*4+4).
// Lane (r4=lane>>4, sg=lane&15) holds S[r4][sg*4..+4) fp32.
__global__ __launch_bounds__(64, 1) void scan_kernel(
    const bf16* __restrict__ q, const bf16* __restrict__ k,
    const bf16* __restrict__ v, const bf16* __restrict__ a,
    const float* __restrict__ betab, const float* __restrict__ gkk,
    bf16* __restrict__ o)
{
  const int blk = blockIdx.x;
  const int qd = blk >> 5;           // DV slice 0..15 (4 rows each)
  const int bh = blk & 31;
  const int b = bh >> 4, h = bh & 15;
  const int lane = threadIdx.x;      // single wave
  const int r4 = lane >> 4;          // local row 0..3
  const int sg = lane & 15;

  // transposed chunk staging: [sg][18 slots of 4 bf16] (144B stride)
  __shared__ __align__(16) __bf16 skT[2][16][72];    // 4608 B
  __shared__ __align__(16) __bf16 sqT[2][16][72];    // 4608 B
  __shared__ __align__(16) __bf16 svaT[2][2][4][16]; // 512 B [buf][v/a][row][step]
  __shared__ __align__(16) float  so[16][68];        // 4352 B (balanced banks)
  __shared__ __align__(16) __bf16 so2[16][4];        // reduced outputs
  __shared__ float sbeta[2048];                      // 8 KB
  __shared__ float sG[2048];                         // 8 KB  beta*kk

  {
    const float* bp = betab + (size_t)h * 4096 + b * 2048;
    const float* gp = gkk   + (size_t)h * 4096 + b * 2048;
    for (int t = lane; t < 2048; t += 64) { sbeta[t] = bp[t]; sG[t] = gp[t]; }
  }

  const size_t bkq = (size_t)b * 2048 * 1024 + h * 64;   // k/q plane base
  const size_t bva = bkq + qd * 4;                       // v/a/o slice base
  const __bf16* kp = (const __bf16*)k;
  const __bf16* qp = (const __bf16*)q;

  const int g_st = lane >> 3;          // staging step-in-group 0..7
  const int g_cg = (lane & 7) * 8;     // staging col (bf16 units)
  const int sgp  = (lane & 7) * 2;     // sg-slice pair base for commit
  const int va_vh = (lane >> 4) & 1;   // lanes 0-15: v, 16-31: a
  const int va_st = lane & 15;

  bf16x8 pk[2], pq[2];
  bf16x4v pva;
  auto fetch = [&](int t0) {
#pragma unroll
    for (int j = 0; j < 2; ++j) {
      int st = t0 + j * 8 + g_st;
      pk[j] = *(const bf16x8*)(kp + bkq + (size_t)st * 1024 + g_cg);
      pq[j] = *(const bf16x8*)(qp + bkq + (size_t)st * 1024 + g_cg);
    }
    if (lane < 32) {
      const __bf16* src = va_vh ? (const __bf16*)a : (const __bf16*)v;
      pva = *(const bf16x4v*)(src + bva + (size_t)(t0 + va_st) * 1024);
    }
  };
  auto commit = [&](int cb) {
#pragma unroll
    for (int j = 0; j < 2; ++j) {
      int stl = j * 8 + g_st;          // step in chunk 0..15
      u32x4 wk = __builtin_bit_cast(u32x4, pk[j]);
      u32x4 wq = __builtin_bit_cast(u32x4, pq[j]);
      u32x2 lo, hi;
      lo[0] = wk[0]; lo[1] = wk[1]; hi[0] = wk[2]; hi[1] = wk[3];
      *(u32x2*)&skT[cb][sgp][stl * 4]     = lo;
      *(u32x2*)&skT[cb][sgp + 1][stl * 4] = hi;
      lo[0] = wq[0]; lo[1] = wq[1]; hi[0] = wq[2]; hi[1] = wq[3];
      *(u32x2*)&sqT[cb][sgp][stl * 4]     = lo;
      *(u32x2*)&sqT[cb][sgp + 1][stl * 4] = hi;
    }
    if (lane < 32) {
#pragma unroll
      for (int r = 0; r < 4; ++r) svaT[cb][va_vh][r][va_st] = pva[r];
    }
  };

  fetch(0); commit(0);

  f32x2 S2[2];
  S2[0] = {0.f, 0.f}; S2[1] = {0.f, 0.f};
  f32x2 Sold0 = {0.f, 0.f}, Sold1 = {0.f, 0.f};
  float u = 0.f, cc = 0.f, aprev = 0.f;
  __syncthreads();

  auto unpk = [&](unsigned int w) -> f32x2 {
    f32x2 r; r[0] = bcf(w << 16); r[1] = bcf(w & 0xffff0000u); return r;
  };

  for (int c = 0; c < 128; ++c) {
    const int buf = c & 1;
    const bool hasNext = (c + 1 < 128);

    if (hasNext) fetch((c + 1) * 16);   // issue VMEM before the lgkm wait below

    // ---- bulk LDS -> reg: one wait per chunk ----
    u32x4 kw[8], qw[8], vw[2], aw[2];
#pragma unroll
    for (int r = 0; r < 8; ++r) {
      kw[r] = *(const u32x4*)&skT[buf][sg][r * 8];
      qw[r] = *(const u32x4*)&sqT[buf][sg][r * 8];
    }
    vw[0] = *(const u32x4*)&svaT[buf][0][r4][0];
    vw[1] = *(const u32x4*)&svaT[buf][0][r4][8];
    aw[0] = *(const u32x4*)&svaT[buf][1][r4][0];
    aw[1] = *(const u32x4*)&svaT[buf][1][r4][8];
    f32x4 bw[4], gw[4];
#pragma unroll
    for (int r = 0; r < 4; ++r) {
      bw[r] = *(const f32x4*)&sbeta[c * 16 + r * 4];
      gw[r] = *(const f32x4*)&sG[c * 16 + r * 4];
    }
    // ASM PIN: "+v" makes every staged value an input+output of the (empty)
    // asm -> all 28 ds_reads must materialize HERE; later uses must come from
    // registers (IR-level re-sinking/remat would be incorrect). R3/R4's
    // sched_barrier could not enforce this (sinking happens pre-MIR).
    asm volatile("" : "+v"(kw[0]), "+v"(kw[1]), "+v"(kw[2]), "+v"(kw[3]),
                      "+v"(kw[4]), "+v"(kw[5]), "+v"(kw[6]), "+v"(kw[7]),
                      "+v"(qw[0]), "+v"(qw[1]), "+v"(qw[2]), "+v"(qw[3]),
                      "+v"(qw[4]), "+v"(qw[5]), "+v"(qw[6]), "+v"(qw[7]));
    asm volatile("" : "+v"(vw[0]), "+v"(vw[1]), "+v"(aw[0]), "+v"(aw[1]),
                      "+v"(bw[0]), "+v"(bw[1]), "+v"(bw[2]), "+v"(bw[3]),
                      "+v"(gw[0]), "+v"(gw[1]), "+v"(gw[2]), "+v"(gw[3]));

    // ---- chunk preamble: u for step 0 = Sold . k_0  (Sold = S_{t0-2}) ----
    f32x2 k2cur[2];
    k2cur[0] = unpk(kw[0][0]);
    k2cur[1] = unpk(kw[0][1]);
    {
      f32x2 dd = Sold0 * k2cur[0];
      dd += Sold1 * k2cur[1];
      float un = dd[0] + dd[1];
      un += dpp_f<0xB1>(un);
      un += dpp_f<0x4E>(un);
      un += dpp_f<0x141>(un);
      un += dpp_f<0x140>(un);
      u = un;   // c==0: Sold=0 -> u=0, correct
    }

#pragma unroll
    for (int i = 0; i < 16; ++i) {
      float bt = bw[i >> 2][i & 3];
      float Gt = gw[i >> 2][i & 3];
      unsigned int wv = vw[i >> 3][(i >> 1) & 3];
      unsigned int wa = aw[i >> 3][(i >> 1) & 3];
      float vr = (i & 1) ? bcf(wv & 0xffff0000u) : bcf(wv << 16);
      float ar = (i & 1) ? bcf(wa & 0xffff0000u) : bcf(wa << 16);

      // u_{t+1} = S_{t-1}.k_{t+1}  (off-chain; full iteration of slack)
      float unxt = 0.f;
      f32x2 k2n[2];
      if (i < 15) {
        k2n[0] = unpk(kw[(i + 1) >> 1][((i + 1) & 1) * 2]);
        k2n[1] = unpk(kw[(i + 1) >> 1][((i + 1) & 1) * 2 + 1]);
        f32x2 dd = S2[0] * k2n[0];
        dd += S2[1] * k2n[1];
        unxt = dd[0] + dd[1];
        unxt += dpp_f<0xB1>(unxt);
        unxt += dpp_f<0x4E>(unxt);
        unxt += dpp_f<0x141>(unxt);
        unxt += dpp_f<0x140>(unxt);
      } else {
        Sold0 = S2[0]; Sold1 = S2[1];   // S_{t-1} for next chunk's preamble
      }

      // serial chain: cc_t = A_t - cc_{t-1} * G_t  (1 fma)
      float A = bt * __builtin_fmaf(aprev, u, -vr);
      cc = __builtin_fmaf(-cc, Gt, A);

      // S update + output (off-chain throughput)
      f32x2 q2[2];
      q2[0] = unpk(qw[i >> 1][(i & 1) * 2]);
      q2[1] = unpk(qw[i >> 1][(i & 1) * 2 + 1]);
      const f32x2 cc2 = {cc, cc}, arv = {ar, ar};
      f32x2 oo;
      {
        f32x2 t0 = cc2 * k2cur[0]; S2[0] = arv * S2[0] - t0; oo = S2[0] * q2[0];
        f32x2 t1 = cc2 * k2cur[1]; S2[1] = arv * S2[1] - t1; oo += S2[1] * q2[1];
      }
      so[i][lane] = oo[0] + oo[1];       // deferred output partial

      aprev = ar;
      if (i < 15) { k2cur[0] = k2n[0]; k2cur[1] = k2n[1]; u = unxt; }
    }

    // deferred output reduction + coalesced store (single wave: ds-ordered)
    {
      int st = lane >> 2, rr = lane & 3;      // 64 outputs: 16 steps x 4 rows
      float4 A0 = *(const float4*)&so[st][rr * 16];
      float4 A1 = *(const float4*)&so[st][rr * 16 + 4];
      float4 A2 = *(const float4*)&so[st][rr * 16 + 8];
      float4 A3 = *(const float4*)&so[st][rr * 16 + 12];
      float s = (((A0.x + A0.y) + (A0.z + A0.w)) + ((A1.x + A1.y) + (A1.z + A1.w)))
              + (((A2.x + A2.y) + (A2.z + A2.w)) + ((A3.x + A3.y) + (A3.z + A3.w)));
      so2[st][rr] = cvt_bf16(s);
    }
    if (lane < 16)
      *(bf16x4v*)((__bf16*)o + bva + (size_t)(c * 16 + lane) * 1024) =
          *(const bf16x4v*)&so2[lane][0];

    if (hasNext) commit(buf ^ 1);
    __syncthreads();
  }
}

// LayerNorm over DV=64 per (b,t,h) row, *ln_w+ln_b, *gate -> bf16
__global__ __launch_bounds__(256) void ln_gate_kernel(
    const bf16* __restrict__ o, const bf16* __restrict__ g,
    const float* __restrict__ lnw, const float* __restrict__ lnb,
    bf16* __restrict__ out)
{
  int row = blockIdx.x * 4 + (threadIdx.x >> 6);
  int lane = threadIdx.x & 63;
  size_t idx = (size_t)row * 64 + lane;
  float xv = (float)o[idx];
  float mu = xv;
#pragma unroll
  for (int s = 1; s < 64; s <<= 1) mu += __shfl_xor(mu, s);
  mu *= (1.f / 64.f);
  float d = xv - mu;
  float vv = d * d;
#pragma unroll
  for (int s = 1; s < 64; s <<= 1) vv += __shfl_xor(vv, s);
  vv *= (1.f / 64.f);
  float y = d * rsqrtf(vv + 1e-5f) * lnw[lane] + lnb[lane];
  y *= (float)g[idx];
  out[idx] = (bf16)y;
}

extern "C" void kernel_launch(void* const* d_in, const int* in_sizes, int n_in,
                              void* d_out, int out_size, void* d_ws, size_t ws_size,
                              hipStream_t stream)
{
  const float* x   = (const float*)d_in[0];
  const float* Wq  = (const float*)d_in[1];
  const float* Wk  = (const float*)d_in[2];
  const float* Wv  = (const float*)d_in[3];
  const float* Wa  = (const float*)d_in[4];
  const float* ba  = (const float*)d_in[5];
  const float* Wb  = (const float*)d_in[6];
  const float* bb  = (const float*)d_in[7];
  const float* Wg  = (const float*)d_in[8];
  const float* Wo  = (const float*)d_in[9];
  const float* qcw = (const float*)d_in[10];
  const float* qcb = (const float*)d_in[11];
  const float* kcw = (const float*)d_in[12];
  const float* kcb = (const float*)d_in[13];
  const float* vcw = (const float*)d_in[14];
  const float* vcb = (const float*)d_in[15];
  const float* lnw = (const float*)d_in[16];
  const float* lnb = (const float*)d_in[17];

  const int M = 4096, HID = 1024;
  const size_t PLANE = (size_t)M * HID;
  const size_t PB = PLANE * sizeof(bf16);          // 8 MB bf16 plane

  char* ws = (char*)d_ws;
  float* outf  = (float*)d_out;
  float* betab = outf;                               // [0,256K)
  float* gkk   = (float*)((char*)d_out + 256 * 1024);// [256K,512K)
  bf16*  ob    = (bf16*)((char*)d_out + 8 * 1024 * 1024); // [8M,16M)

  const bool rich = (ws_size >= 5 * PB + 1024);

  dim3 blk(256);
  dim3 g8(8, 32);
  int nconv = (int)(PLANE / 256);

  if (rich) {
    bf16* P0 = (bf16*)(ws);
    bf16* P1 = (bf16*)(ws + PB);
    bf16* P2 = (bf16*)(ws + 2 * PB);
    bf16* P3 = (bf16*)(ws + 3 * PB);
    bf16* P4 = (bf16*)(ws + 4 * PB);
    bf16* xb = (bf16*)d_out;                         // [0,8M), dead before betab

    cvt_plane_kernel<<<(int)(PLANE / 1024), blk, 0, stream>>>(x, xb);
    // zq->P0, zk->P1, zv->P2, a(sigmoid+ba)->P3
    mega_gemm<<<dim3(32, 32), blk, 0, stream>>>(xb, Wq, Wk, Wv, Wa, ba, P0, M, HID);
    conv_silu_kernel<<<nconv, blk, 0, stream>>>(P0, qcw, qcb, P4, 1.f);     // q->P4
    conv_silu_kernel<<<nconv, blk, 0, stream>>>(P1, kcw, kcb, P0, 0.125f);  // k->P0
    conv_silu_kernel<<<nconv, blk, 0, stream>>>(P2, vcw, vcb, P1, 1.f);     // v->P1
    gemm_bt<3, false><<<g8, blk, 0, stream>>>(xb, Wg, nullptr, nullptr, P2, M, HID, HID); // g->P2
    gemm_bt<5, false><<<dim3(1, 32), blk, 0, stream>>>(xb, Wb, bb, betab, nullptr, M, 16, HID);
    kk_kernel<<<1024, blk, 0, stream>>>(P0, betab, gkk);
    scan_kernel<<<512, dim3(64), 0, stream>>>(P4, P0, P1, P3, betab, gkk, ob);
    ln_gate_kernel<<<M * 16 / 4, blk, 0, stream>>>(ob, P2, lnw, lnb, P3);   // ->P3
    gemm_bt<4, false><<<g8, blk, 0, stream>>>(P3, Wo, nullptr, outf, nullptr, M, HID, HID);
  } else {
    bf16* P  = (bf16*)(ws);
    bf16* qb = (bf16*)(ws + PB);
    bf16* kb = (bf16*)(ws + 2 * PB);
    bf16* vb = (bf16*)(ws + 3 * PB);

    gemm_bt<2, true><<<g8, blk, 0, stream>>>(x, Wq, nullptr, nullptr, P, M, HID, HID);
    conv_silu_kernel<<<nconv, blk, 0, stream>>>(P, qcw, qcb, qb, 1.f);
    gemm_bt<2, true><<<g8, blk, 0, stream>>>(x, Wk, nullptr, nullptr, P, M, HID, HID);
    conv_silu_kernel<<<nconv, blk, 0, stream>>>(P, kcw, kcb, kb, 0.125f);
    gemm_bt<2, true><<<g8, blk, 0, stream>>>(x, Wv, nullptr, nullptr, P, M, HID, HID);
    conv_silu_kernel<<<nconv, blk, 0, stream>>>(P, vcw, vcb, vb, 1.f);
    gemm_bt<3, true><<<g8, blk, 0, stream>>>(x, Wa, ba, nullptr, P, M, HID, HID);
    gemm_bt<5, true><<<dim3(1, 32), blk, 0, stream>>>(x, Wb, bb, betab, nullptr, M, 16, HID);
    kk_kernel<<<1024, blk, 0, stream>>>(kb, betab, gkk);
    scan_kernel<<<512, dim3(64), 0, stream>>>(qb, kb, vb, P, betab, gkk, ob);
    gemm_bt<3, true><<<g8, blk, 0, stream>>>(x, Wg, nullptr, nullptr, qb, M, HID, HID);
    ln_gate_kernel<<<M * 16 / 4, blk, 0, stream>>>(ob, qb, lnw, lnb, kb);
    gemm_bt<4, false><<<g8, blk, 0, stream>>>(kb, Wo, nullptr, outf, nullptr, M, HID, HID);
  }
}